// Round 4
// baseline (395.963 us; speedup 1.0000x reference)
//
#include <hip/hip_runtime.h>
#include <cstddef>

// ---------------------------------------------------------------------------
// 2-layer GAT forward, f32, CSR-gather formulation (no float atomics).
// R4: XCD-segmented CSR build. dst range split into 8 segments; segment r is
// processed only by blocks with blockIdx%8==r (consecutive blocks round-robin
// across the 8 XCDs), so all counts/csr writes for a line stay in one XCD's
// L2 -> full write-combining instead of 64B/store false-sharing evictions.
// Scans fused into one single-block kernel. Gather kernels unchanged from R3.
// ---------------------------------------------------------------------------

#define NSEG 8

__device__ __forceinline__ float lrelu(float x) { return x > 0.f ? x : 0.2f * x; }
__device__ __forceinline__ int iadd(int* p, int v) {
  return __hip_atomic_fetch_add(p, v, __ATOMIC_RELAXED, __HIP_MEMORY_SCOPE_AGENT);
}

// ---- CSR build ------------------------------------------------------------

__global__ __launch_bounds__(256) void k_hist_seg(
    const int* __restrict__ ei, int* __restrict__ counts, int E, int n, int W)
{
  const int seg = blockIdx.x & (NSEG - 1);     // -> XCD (perf heuristic only)
  const int w   = blockIdx.x >> 3;
  const int ss  = (n + NSEG - 1) / NSEG;
  const int lo  = seg * ss;
  const int hi  = (lo + ss < n) ? lo + ss : n;
  const int tot = E + n;
  for (int e = w * 256 + threadIdx.x; e < tot; e += W * 256) {
    int d = (e < E) ? ei[E + e] : e - E;
    if (d >= lo && d < hi) iadd(&counts[d], 1);
  }
}

// single-block exclusive scan of counts[0..n) -> offs[0..n], offs[n]=total
__global__ __launch_bounds__(1024) void k_scan(
    const int* __restrict__ counts, int* __restrict__ offs, int n)
{
  __shared__ int sp[1024];
  const int tid = threadIdx.x;
  const int per = (n + 1023) / 1024;
  const int i0 = tid * per;
  const int i1 = (i0 + per < n) ? i0 + per : n;
  int sum = 0;
  for (int i = i0; i < i1; ++i) sum += counts[i];
  sp[tid] = sum; __syncthreads();
  for (int off = 1; off < 1024; off <<= 1) {
    int v = (tid >= off) ? sp[tid - off] : 0;
    __syncthreads();
    sp[tid] += v;
    __syncthreads();
  }
  int excl = sp[tid] - sum;
  for (int i = i0; i < i1; ++i) { int c = counts[i]; offs[i] = excl; excl += c; }
  if (tid == 1023) offs[n] = excl;
}

__global__ __launch_bounds__(256) void k_scatter_seg(
    const int* __restrict__ ei, const int* __restrict__ offs,
    int* __restrict__ counts, int* __restrict__ csr, int E, int n, int W)
{
  const int seg = blockIdx.x & (NSEG - 1);
  const int w   = blockIdx.x >> 3;
  const int ss  = (n + NSEG - 1) / NSEG;
  const int lo  = seg * ss;
  const int hi  = (lo + ss < n) ? lo + ss : n;
  const int tot = E + n;
  for (int e = w * 256 + threadIdx.x; e < tot; e += W * 256) {
    int d = (e < E) ? ei[E + e] : e - E;
    if (d < lo || d >= hi) continue;
    int s = (e < E) ? ei[e] : d;
    int old = iadd(&counts[d], -1);
    csr[offs[d] + old - 1] = s;
  }
}

// ---- K1: embedding gather + x@W1 (128->64) + attention dots ---------------
__global__ __launch_bounds__(256) void k_embed_proj1(
    const int* __restrict__ x_ids, const float* __restrict__ emb,
    const float* __restrict__ W1, const float* __restrict__ a_src1,
    const float* __restrict__ a_dst1,
    float* __restrict__ xp1, float* __restrict__ asrc1, float* __restrict__ adst1,
    int n)
{
  __shared__ float sW[128 * 64];
  __shared__ float sx[4][128];
  for (int i = threadIdx.x; i < 128 * 64; i += 256) sW[i] = W1[i];
  const int ln = threadIdx.x >> 6;
  const int ch = threadIdx.x & 63;
  const int hh = ch >> 3, cc = ch & 7;
  const float as = a_src1[ch];
  const float ad = a_dst1[ch];
  for (int g = 0; g < 8; ++g) {
    const int base = blockIdx.x * 32 + g * 4;
    __syncthreads();
    for (int i = threadIdx.x; i < 512; i += 256) {
      int l = i >> 7, k = i & 127;
      int node = base + l;
      sx[l][k] = (node < n) ? emb[(size_t)x_ids[node] * 128 + k] : 0.f;
    }
    __syncthreads();
    const int node = base + ln;
    float acc = 0.f;
#pragma unroll
    for (int k = 0; k < 128; ++k) acc = fmaf(sx[ln][k], sW[k * 64 + ch], acc);
    float vs = acc * as, vd = acc * ad;
    vs += __shfl_xor(vs, 1); vs += __shfl_xor(vs, 2); vs += __shfl_xor(vs, 4);
    vd += __shfl_xor(vd, 1); vd += __shfl_xor(vd, 2); vd += __shfl_xor(vd, 4);
    if (node < n) {
      xp1[(size_t)node * 64 + ch] = acc;
      if (cc == 0) { asrc1[node * 8 + hh] = vs; adst1[node * 8 + hh] = vd; }
    }
  }
}

// ---- G1: layer-1 gather-aggregate + ELU + fused 64->20 projection ---------
__global__ __launch_bounds__(256) void k_gather1(
    const int* __restrict__ offs, const int* __restrict__ csr,
    const float* __restrict__ asrc1, const float* __restrict__ adst1,
    const float* __restrict__ xp1, const float* __restrict__ b1,
    const float* __restrict__ W2, const float* __restrict__ a_src2,
    const float* __restrict__ a_dst2,
    float* __restrict__ xp2, float* __restrict__ asrc2, float* __restrict__ adst2,
    int n)
{
  __shared__ float sW[64 * 20];
  __shared__ float sh[4][64];
  for (int i = threadIdx.x; i < 64 * 20; i += 256) sW[i] = W2[i];
  __syncthreads();
  const int wid = threadIdx.x >> 6;
  const int ln  = threadIdx.x & 63;
  const int eslot = ln >> 4;
  const int q     = ln & 15;
  const int hh    = q >> 1;
  const int d = blockIdx.x * 4 + wid;
  const bool valid = d < n;
  const int beg = valid ? offs[d] : 0;
  const int end = valid ? offs[d + 1] : 0;
  const float adT = valid ? adst1[(size_t)d * 8 + hh] : 0.f;
  float a0 = 0.f, a1 = 0.f, a2 = 0.f, a3 = 0.f, den = 0.f;
#pragma unroll 4
  for (int jb = beg + eslot; jb < end; jb += 4) {
    const int s = csr[jb];
    const float p = __expf(lrelu(asrc1[(size_t)s * 8 + hh] + adT));
    const float4 v = *(const float4*)(xp1 + (size_t)s * 64 + q * 4);
    a0 = fmaf(p, v.x, a0); a1 = fmaf(p, v.y, a1);
    a2 = fmaf(p, v.z, a2); a3 = fmaf(p, v.w, a3);
    den += p;
  }
#pragma unroll
  for (int off = 16; off < 64; off <<= 1) {
    a0 += __shfl_xor(a0, off); a1 += __shfl_xor(a1, off);
    a2 += __shfl_xor(a2, off); a3 += __shfl_xor(a3, off);
    den += __shfl_xor(den, off);
  }
  if (valid && eslot == 0) {
    const float inv = 1.f / den;
    float t0 = a0 * inv + b1[q * 4 + 0];
    float t1 = a1 * inv + b1[q * 4 + 1];
    float t2 = a2 * inv + b1[q * 4 + 2];
    float t3 = a3 * inv + b1[q * 4 + 3];
    sh[wid][q * 4 + 0] = t0 > 0.f ? t0 : expm1f(t0);
    sh[wid][q * 4 + 1] = t1 > 0.f ? t1 : expm1f(t1);
    sh[wid][q * 4 + 2] = t2 > 0.f ? t2 : expm1f(t2);
    sh[wid][q * 4 + 3] = t3 > 0.f ? t3 : expm1f(t3);
  }
  __syncthreads();
  float acc2 = 0.f;
  if (valid && ln < 20) {
#pragma unroll 16
    for (int k = 0; k < 64; ++k) acc2 = fmaf(sh[wid][k], sW[k * 20 + ln], acc2);
    xp2[(size_t)d * 20 + ln] = acc2;
  }
  float vs = (valid && ln < 20) ? acc2 * a_src2[ln] : 0.f;
  float vd = (valid && ln < 20) ? acc2 * a_dst2[ln] : 0.f;
#pragma unroll
  for (int off = 1; off < 32; off <<= 1) {
    vs += __shfl_xor(vs, off);
    vd += __shfl_xor(vd, off);
  }
  if (valid && ln == 0) { asrc2[d] = vs; adst2[d] = vd; }
}

// ---- G2: layer-2 gather-aggregate + fused log_softmax -> out --------------
__global__ __launch_bounds__(256) void k_gather2(
    const int* __restrict__ offs, const int* __restrict__ csr,
    const float* __restrict__ asrc2, const float* __restrict__ adst2,
    const float* __restrict__ xp2, const float* __restrict__ b2,
    float* __restrict__ out, int n)
{
  const int wid = threadIdx.x >> 6, ln = threadIdx.x & 63;
  const int eslot = ln >> 2, q = ln & 3;
  const int d = blockIdx.x * 4 + wid;
  if (d >= n) return;
  const int beg = offs[d], end = offs[d + 1];
  const float adT = adst2[d];
  float acc[5] = {0.f, 0.f, 0.f, 0.f, 0.f};
  float den = 0.f;
#pragma unroll 2
  for (int jb = beg + eslot; jb < end; jb += 16) {
    const int s = csr[jb];
    const float p = __expf(lrelu(asrc2[s] + adT));
    const float* row = xp2 + (size_t)s * 20 + q * 5;
#pragma unroll
    for (int j = 0; j < 5; ++j) acc[j] = fmaf(p, row[j], acc[j]);
    den += p;
  }
#pragma unroll
  for (int off = 4; off < 64; off <<= 1) {
#pragma unroll
    for (int j = 0; j < 5; ++j) acc[j] += __shfl_xor(acc[j], off);
    den += __shfl_xor(den, off);
  }
  const float inv = 1.f / den;
  float o[5], mx = -1e30f;
#pragma unroll
  for (int j = 0; j < 5; ++j) {
    o[j] = acc[j] * inv + b2[q * 5 + j];
    mx = fmaxf(mx, o[j]);
  }
  mx = fmaxf(mx, __shfl_xor(mx, 1));
  mx = fmaxf(mx, __shfl_xor(mx, 2));
  float ss = 0.f;
#pragma unroll
  for (int j = 0; j < 5; ++j) ss += __expf(o[j] - mx);
  ss += __shfl_xor(ss, 1);
  ss += __shfl_xor(ss, 2);
  const float lse = mx + __logf(ss);
  if (eslot == 0) {
#pragma unroll
    for (int j = 0; j < 5; ++j) out[(size_t)d * 20 + q * 5 + j] = o[j] - lse;
  }
}

// ---------------------------------------------------------------------------

extern "C" void kernel_launch(void* const* d_in, const int* in_sizes, int n_in,
                              void* d_out, int out_size, void* d_ws, size_t ws_size,
                              hipStream_t stream)
{
  const int*   x_ids  = (const int*)d_in[0];
  const int*   ei     = (const int*)d_in[1];   // [2,E]: [0..E)=src, [E..2E)=dst
  const float* emb    = (const float*)d_in[2];
  const float* W1     = (const float*)d_in[3];
  const float* a_src1 = (const float*)d_in[4];
  const float* a_dst1 = (const float*)d_in[5];
  const float* b1     = (const float*)d_in[6];
  const float* W2     = (const float*)d_in[7];
  const float* a_src2 = (const float*)d_in[8];
  const float* a_dst2 = (const float*)d_in[9];
  const float* b2     = (const float*)d_in[10];
  float* out = (float*)d_out;

  const int n = in_sizes[0];
  const int E = in_sizes[1] / 2;

  float* ws    = (float*)d_ws;
  float* xp1   = ws;                          // n*64
  float* asrc1 = xp1   + (size_t)n * 64;      // n*8
  float* adst1 = asrc1 + (size_t)n * 8;       // n*8
  float* xp2   = adst1 + (size_t)n * 8;       // n*20
  float* asrc2 = xp2   + (size_t)n * 20;      // n
  float* adst2 = asrc2 + (size_t)n;           // n
  int*   counts = (int*)(adst2 + (size_t)n);  // n (zeroed each call)
  int*   offs   = counts + n;                 // n+1
  int*   csr    = offs + n + 1;               // E+n

  hipMemsetAsync(counts, 0, (size_t)n * sizeof(int), stream);

  const int W = 64;                           // blocks per segment
  k_hist_seg<<<NSEG * W, 256, 0, stream>>>(ei, counts, E, n, W);
  k_scan<<<1, 1024, 0, stream>>>(counts, offs, n);
  k_scatter_seg<<<NSEG * W, 256, 0, stream>>>(ei, offs, counts, csr, E, n, W);

  k_embed_proj1<<<(n + 31) / 32, 256, 0, stream>>>(
      x_ids, emb, W1, a_src1, a_dst1, xp1, asrc1, adst1, n);

  k_gather1<<<(n + 3) / 4, 256, 0, stream>>>(
      offs, csr, asrc1, adst1, xp1, b1, W2, a_src2, a_dst2,
      xp2, asrc2, adst2, n);

  k_gather2<<<(n + 3) / 4, 256, 0, stream>>>(
      offs, csr, asrc2, adst2, xp2, b2, out, n);
}

// Round 5
// 314.197 us; speedup vs baseline: 1.2602x; 1.2602x over previous
//
#include <hip/hip_runtime.h>
#include <cstddef>

// ---------------------------------------------------------------------------
// 2-layer GAT forward, f32, CSR-gather formulation.
// R5: CSR build via single-pass radix partition (bucket = dst>>8) with
// block-local dense writes, then per-bucket LDS-cursor scatter. All random
// global writes are confined to one block (one CU -> one XCD L2) -> full
// write-combining. No per-dst global atomics anywhere.
// Requires n < 65536 (src id packed in 16 bits); here n = 50000.
// ---------------------------------------------------------------------------

#define EPB 2048   // edges per k_part block

__device__ __forceinline__ float lrelu(float x) { return x > 0.f ? x : 0.2f * x; }
__device__ __forceinline__ int iadd(int* p, int v) {
  return __hip_atomic_fetch_add(p, v, __ATOMIC_RELAXED, __HIP_MEMORY_SCOPE_AGENT);
}

// ---- CSR build ------------------------------------------------------------

// bucket histogram (LDS-aggregated; 256 global atomics per block)
__global__ __launch_bounds__(256) void k_bhist(
    const int* __restrict__ ei, int* __restrict__ bhist, int E)
{
  __shared__ int h[256];
  h[threadIdx.x] = 0; __syncthreads();
  for (int e = blockIdx.x * 256 + threadIdx.x; e < E; e += gridDim.x * 256)
    atomicAdd(&h[ei[E + e] >> 8], 1);
  __syncthreads();
  int c = h[threadIdx.x];
  if (c) iadd(&bhist[threadIdx.x], c);
}

// scan bucket sizes -> bufOffs[0..nb], tails
__global__ __launch_bounds__(256) void k_bscan(
    const int* __restrict__ bhist, int* __restrict__ bufOffs,
    int* __restrict__ tail, int nb)
{
  __shared__ int sp[256];
  const int tid = threadIdx.x;
  int v = (tid < nb) ? bhist[tid] : 0;
  sp[tid] = v; __syncthreads();
  for (int off = 1; off < 256; off <<= 1) {
    int t = (tid >= off) ? sp[tid - off] : 0;
    __syncthreads();
    sp[tid] += t;
    __syncthreads();
  }
  int excl = sp[tid] - v;
  if (tid < nb) { bufOffs[tid] = excl; tail[tid] = excl; }
  if (tid == 255) bufOffs[nb] = sp[255];
}

// partition edges into buckets; dense block-local writes into reserved ranges
__global__ __launch_bounds__(256) void k_part(
    const int* __restrict__ ei, int* __restrict__ tail,
    int* __restrict__ buf, int E)
{
  __shared__ int sPair[EPB];
  __shared__ unsigned char sKey[EPB];
  __shared__ int sHist[256];
  __shared__ int sBase[256];
  const int tid = threadIdx.x;
  sHist[tid] = 0; __syncthreads();
  const int e0 = blockIdx.x * EPB;
  int m = E - e0; if (m > EPB) m = EPB;
  for (int i = tid; i < m; i += 256) {
    int d = ei[E + e0 + i], s = ei[e0 + i];
    sPair[i] = ((d & 255) << 16) | s;
    int b = d >> 8;
    sKey[i] = (unsigned char)b;
    atomicAdd(&sHist[b], 1);
  }
  __syncthreads();
  int c = sHist[tid];
  sBase[tid] = c ? iadd(&tail[tid], c) : 0;
  sHist[tid] = 0;                       // reuse as cursor
  __syncthreads();
  for (int i = tid; i < m; i += 256) {
    int b = sKey[i];
    int off = atomicAdd(&sHist[b], 1);
    buf[sBase[b] + off] = sPair[i];
  }
}

// per-bucket per-dst counts (incl. self-loop), written sequentially
__global__ __launch_bounds__(256) void k_chist(
    const int* __restrict__ buf, const int* __restrict__ bufOffs,
    int* __restrict__ counts, int n)
{
  __shared__ int h[256];
  const int b = blockIdx.x, tid = threadIdx.x;
  const int d = (b << 8) + tid;
  h[tid] = (d < n) ? 1 : 0;             // self-loop
  __syncthreads();
  const int lo = bufOffs[b], hi = bufOffs[b + 1];
  for (int i = lo + tid; i < hi; i += 256)
    atomicAdd(&h[(buf[i] >> 16) & 255], 1);
  __syncthreads();
  if (d < n) counts[d] = h[tid];
}

// single-block exclusive scan of counts[0..n) -> offs[0..n]
__global__ __launch_bounds__(1024) void k_scan(
    const int* __restrict__ counts, int* __restrict__ offs, int n)
{
  __shared__ int sp[1024];
  const int tid = threadIdx.x;
  const int per = (n + 1023) / 1024;
  const int i0 = tid * per;
  const int i1 = (i0 + per < n) ? i0 + per : n;
  int sum = 0;
  for (int i = i0; i < i1; ++i) sum += counts[i];
  sp[tid] = sum; __syncthreads();
  for (int off = 1; off < 1024; off <<= 1) {
    int v = (tid >= off) ? sp[tid - off] : 0;
    __syncthreads();
    sp[tid] += v;
    __syncthreads();
  }
  int excl = sp[tid] - sum;
  for (int i = i0; i < i1; ++i) { int c = counts[i]; offs[i] = excl; excl += c; }
  if (tid == 1023) offs[n] = excl;
}

// per-bucket scatter into csr with LDS cursors; self-loop first
__global__ __launch_bounds__(256) void k_cscat(
    const int* __restrict__ buf, const int* __restrict__ bufOffs,
    const int* __restrict__ offs, int* __restrict__ csr, int n)
{
  __shared__ int cur[256];
  const int b = blockIdx.x, tid = threadIdx.x;
  const int d = (b << 8) + tid;
  if (d < n) { int o = offs[d]; csr[o] = d; cur[tid] = o + 1; }
  __syncthreads();
  const int lo = bufOffs[b], hi = bufOffs[b + 1];
  for (int i = lo + tid; i < hi; i += 256) {
    int p = buf[i];
    int pos = atomicAdd(&cur[(p >> 16) & 255], 1);
    csr[pos] = p & 0xFFFF;
  }
}

// ---- K1: embedding gather + x@W1 (128->64) + attention dots ---------------
__global__ __launch_bounds__(256) void k_embed_proj1(
    const int* __restrict__ x_ids, const float* __restrict__ emb,
    const float* __restrict__ W1, const float* __restrict__ a_src1,
    const float* __restrict__ a_dst1,
    float* __restrict__ xp1, float* __restrict__ asrc1, float* __restrict__ adst1,
    int n)
{
  __shared__ float sW[128 * 64];
  __shared__ float sx[4][128];
  for (int i = threadIdx.x; i < 128 * 64; i += 256) sW[i] = W1[i];
  const int ln = threadIdx.x >> 6;
  const int ch = threadIdx.x & 63;
  const int hh = ch >> 3, cc = ch & 7;
  const float as = a_src1[ch];
  const float ad = a_dst1[ch];
  for (int g = 0; g < 8; ++g) {
    const int base = blockIdx.x * 32 + g * 4;
    __syncthreads();
    for (int i = threadIdx.x; i < 512; i += 256) {
      int l = i >> 7, k = i & 127;
      int node = base + l;
      sx[l][k] = (node < n) ? emb[(size_t)x_ids[node] * 128 + k] : 0.f;
    }
    __syncthreads();
    const int node = base + ln;
    float acc = 0.f;
#pragma unroll
    for (int k = 0; k < 128; ++k) acc = fmaf(sx[ln][k], sW[k * 64 + ch], acc);
    float vs = acc * as, vd = acc * ad;
    vs += __shfl_xor(vs, 1); vs += __shfl_xor(vs, 2); vs += __shfl_xor(vs, 4);
    vd += __shfl_xor(vd, 1); vd += __shfl_xor(vd, 2); vd += __shfl_xor(vd, 4);
    if (node < n) {
      xp1[(size_t)node * 64 + ch] = acc;
      if (cc == 0) { asrc1[node * 8 + hh] = vs; adst1[node * 8 + hh] = vd; }
    }
  }
}

// ---- G1: layer-1 gather-aggregate + ELU + fused 64->20 projection ---------
__global__ __launch_bounds__(256) void k_gather1(
    const int* __restrict__ offs, const int* __restrict__ csr,
    const float* __restrict__ asrc1, const float* __restrict__ adst1,
    const float* __restrict__ xp1, const float* __restrict__ b1,
    const float* __restrict__ W2, const float* __restrict__ a_src2,
    const float* __restrict__ a_dst2,
    float* __restrict__ xp2, float* __restrict__ asrc2, float* __restrict__ adst2,
    int n)
{
  __shared__ float sW[64 * 20];
  __shared__ float sh[4][64];
  for (int i = threadIdx.x; i < 64 * 20; i += 256) sW[i] = W2[i];
  __syncthreads();
  const int wid = threadIdx.x >> 6;
  const int ln  = threadIdx.x & 63;
  const int eslot = ln >> 4;
  const int q     = ln & 15;
  const int hh    = q >> 1;
  const int d = blockIdx.x * 4 + wid;
  const bool valid = d < n;
  const int beg = valid ? offs[d] : 0;
  const int end = valid ? offs[d + 1] : 0;
  const float adT = valid ? adst1[(size_t)d * 8 + hh] : 0.f;
  float a0 = 0.f, a1 = 0.f, a2 = 0.f, a3 = 0.f, den = 0.f;
#pragma unroll 4
  for (int jb = beg + eslot; jb < end; jb += 4) {
    const int s = csr[jb];
    const float p = __expf(lrelu(asrc1[(size_t)s * 8 + hh] + adT));
    const float4 v = *(const float4*)(xp1 + (size_t)s * 64 + q * 4);
    a0 = fmaf(p, v.x, a0); a1 = fmaf(p, v.y, a1);
    a2 = fmaf(p, v.z, a2); a3 = fmaf(p, v.w, a3);
    den += p;
  }
#pragma unroll
  for (int off = 16; off < 64; off <<= 1) {
    a0 += __shfl_xor(a0, off); a1 += __shfl_xor(a1, off);
    a2 += __shfl_xor(a2, off); a3 += __shfl_xor(a3, off);
    den += __shfl_xor(den, off);
  }
  if (valid && eslot == 0) {
    const float inv = 1.f / den;
    float t0 = a0 * inv + b1[q * 4 + 0];
    float t1 = a1 * inv + b1[q * 4 + 1];
    float t2 = a2 * inv + b1[q * 4 + 2];
    float t3 = a3 * inv + b1[q * 4 + 3];
    sh[wid][q * 4 + 0] = t0 > 0.f ? t0 : expm1f(t0);
    sh[wid][q * 4 + 1] = t1 > 0.f ? t1 : expm1f(t1);
    sh[wid][q * 4 + 2] = t2 > 0.f ? t2 : expm1f(t2);
    sh[wid][q * 4 + 3] = t3 > 0.f ? t3 : expm1f(t3);
  }
  __syncthreads();
  float acc2 = 0.f;
  if (valid && ln < 20) {
#pragma unroll 16
    for (int k = 0; k < 64; ++k) acc2 = fmaf(sh[wid][k], sW[k * 20 + ln], acc2);
    xp2[(size_t)d * 20 + ln] = acc2;
  }
  float vs = (valid && ln < 20) ? acc2 * a_src2[ln] : 0.f;
  float vd = (valid && ln < 20) ? acc2 * a_dst2[ln] : 0.f;
#pragma unroll
  for (int off = 1; off < 32; off <<= 1) {
    vs += __shfl_xor(vs, off);
    vd += __shfl_xor(vd, off);
  }
  if (valid && ln == 0) { asrc2[d] = vs; adst2[d] = vd; }
}

// ---- G2: layer-2 gather-aggregate + fused log_softmax -> out --------------
__global__ __launch_bounds__(256) void k_gather2(
    const int* __restrict__ offs, const int* __restrict__ csr,
    const float* __restrict__ asrc2, const float* __restrict__ adst2,
    const float* __restrict__ xp2, const float* __restrict__ b2,
    float* __restrict__ out, int n)
{
  const int wid = threadIdx.x >> 6, ln = threadIdx.x & 63;
  const int eslot = ln >> 2, q = ln & 3;
  const int d = blockIdx.x * 4 + wid;
  if (d >= n) return;
  const int beg = offs[d], end = offs[d + 1];
  const float adT = adst2[d];
  float acc[5] = {0.f, 0.f, 0.f, 0.f, 0.f};
  float den = 0.f;
#pragma unroll 2
  for (int jb = beg + eslot; jb < end; jb += 16) {
    const int s = csr[jb];
    const float p = __expf(lrelu(asrc2[s] + adT));
    const float* row = xp2 + (size_t)s * 20 + q * 5;
#pragma unroll
    for (int j = 0; j < 5; ++j) acc[j] = fmaf(p, row[j], acc[j]);
    den += p;
  }
#pragma unroll
  for (int off = 4; off < 64; off <<= 1) {
#pragma unroll
    for (int j = 0; j < 5; ++j) acc[j] += __shfl_xor(acc[j], off);
    den += __shfl_xor(den, off);
  }
  const float inv = 1.f / den;
  float o[5], mx = -1e30f;
#pragma unroll
  for (int j = 0; j < 5; ++j) {
    o[j] = acc[j] * inv + b2[q * 5 + j];
    mx = fmaxf(mx, o[j]);
  }
  mx = fmaxf(mx, __shfl_xor(mx, 1));
  mx = fmaxf(mx, __shfl_xor(mx, 2));
  float ss = 0.f;
#pragma unroll
  for (int j = 0; j < 5; ++j) ss += __expf(o[j] - mx);
  ss += __shfl_xor(ss, 1);
  ss += __shfl_xor(ss, 2);
  const float lse = mx + __logf(ss);
  if (eslot == 0) {
#pragma unroll
    for (int j = 0; j < 5; ++j) out[(size_t)d * 20 + q * 5 + j] = o[j] - lse;
  }
}

// ---------------------------------------------------------------------------

extern "C" void kernel_launch(void* const* d_in, const int* in_sizes, int n_in,
                              void* d_out, int out_size, void* d_ws, size_t ws_size,
                              hipStream_t stream)
{
  const int*   x_ids  = (const int*)d_in[0];
  const int*   ei     = (const int*)d_in[1];   // [2,E]: [0..E)=src, [E..2E)=dst
  const float* emb    = (const float*)d_in[2];
  const float* W1     = (const float*)d_in[3];
  const float* a_src1 = (const float*)d_in[4];
  const float* a_dst1 = (const float*)d_in[5];
  const float* b1     = (const float*)d_in[6];
  const float* W2     = (const float*)d_in[7];
  const float* a_src2 = (const float*)d_in[8];
  const float* a_dst2 = (const float*)d_in[9];
  const float* b2     = (const float*)d_in[10];
  float* out = (float*)d_out;

  const int n = in_sizes[0];
  const int E = in_sizes[1] / 2;
  const int nb = (n + 255) >> 8;               // buckets of 256 dst ids

  float* ws    = (float*)d_ws;
  float* xp1   = ws;                          // n*64  (aliases buf during build)
  float* asrc1 = xp1   + (size_t)n * 64;      // n*8
  float* adst1 = asrc1 + (size_t)n * 8;       // n*8
  float* xp2   = adst1 + (size_t)n * 8;       // n*20
  float* asrc2 = xp2   + (size_t)n * 20;      // n
  float* adst2 = asrc2 + (size_t)n;           // n
  int*   counts = (int*)(adst2 + (size_t)n);  // n
  int*   offs   = counts + n;                 // n+1
  int*   bhist  = offs + n + 1;               // 256 (zeroed)
  int*   bufOffs= bhist + 256;                // nb+1
  int*   tail   = bufOffs + 257;              // 256
  int*   csr    = tail + 256;                 // E+n
  int*   buf    = (int*)xp1;                  // E   (dead before k_embed_proj1)

  hipMemsetAsync(bhist, 0, 256 * sizeof(int), stream);

  k_bhist<<<256, 256, 0, stream>>>(ei, bhist, E);
  k_bscan<<<1, 256, 0, stream>>>(bhist, bufOffs, tail, nb);
  k_part<<<(E + EPB - 1) / EPB, 256, 0, stream>>>(ei, tail, buf, E);
  k_chist<<<nb, 256, 0, stream>>>(buf, bufOffs, counts, n);
  k_scan<<<1, 1024, 0, stream>>>(counts, offs, n);
  k_cscat<<<nb, 256, 0, stream>>>(buf, bufOffs, offs, csr, n);

  k_embed_proj1<<<(n + 31) / 32, 256, 0, stream>>>(
      x_ids, emb, W1, a_src1, a_dst1, xp1, asrc1, adst1, n);

  k_gather1<<<(n + 3) / 4, 256, 0, stream>>>(
      offs, csr, asrc1, adst1, xp1, b1, W2, a_src2, a_dst2,
      xp2, asrc2, adst2, n);

  k_gather2<<<(n + 3) / 4, 256, 0, stream>>>(
      offs, csr, asrc2, adst2, xp2, b2, out, n);
}

// Round 6
// 239.913 us; speedup vs baseline: 1.6504x; 1.3096x over previous
//
#include <hip/hip_runtime.h>
#include <cstddef>

// ---------------------------------------------------------------------------
// 2-layer GAT forward, f32, CSR-gather formulation.
// R6: drop the global n-element scan. Radix bucket structure gives
//   offs[d] = bufOffs[b] + b*256 + (in-bucket exclusive prefix)
// so a per-bucket kernel (k_coffs) computes offs directly via LDS hist+scan.
// Replaces k_chist + 76us single-block k_scan. Rest unchanged from R5.
// Requires n < 65536 (src id packed in 16 bits); here n = 50000.
// ---------------------------------------------------------------------------

#define EPB 2048   // edges per k_part block

__device__ __forceinline__ float lrelu(float x) { return x > 0.f ? x : 0.2f * x; }
__device__ __forceinline__ int iadd(int* p, int v) {
  return __hip_atomic_fetch_add(p, v, __ATOMIC_RELAXED, __HIP_MEMORY_SCOPE_AGENT);
}

// ---- CSR build ------------------------------------------------------------

// bucket histogram (LDS-aggregated; 256 global atomics per block)
__global__ __launch_bounds__(256) void k_bhist(
    const int* __restrict__ ei, int* __restrict__ bhist, int E)
{
  __shared__ int h[256];
  h[threadIdx.x] = 0; __syncthreads();
  for (int e = blockIdx.x * 256 + threadIdx.x; e < E; e += gridDim.x * 256)
    atomicAdd(&h[ei[E + e] >> 8], 1);
  __syncthreads();
  int c = h[threadIdx.x];
  if (c) iadd(&bhist[threadIdx.x], c);
}

// scan bucket sizes -> bufOffs[0..nb], tails
__global__ __launch_bounds__(256) void k_bscan(
    const int* __restrict__ bhist, int* __restrict__ bufOffs,
    int* __restrict__ tail, int nb)
{
  __shared__ int sp[256];
  const int tid = threadIdx.x;
  int v = (tid < nb) ? bhist[tid] : 0;
  sp[tid] = v; __syncthreads();
  for (int off = 1; off < 256; off <<= 1) {
    int t = (tid >= off) ? sp[tid - off] : 0;
    __syncthreads();
    sp[tid] += t;
    __syncthreads();
  }
  int excl = sp[tid] - v;
  if (tid < nb) { bufOffs[tid] = excl; tail[tid] = excl; }
  if (tid == 255) bufOffs[nb] = sp[255];
}

// partition edges into buckets; dense block-local writes into reserved ranges
__global__ __launch_bounds__(256) void k_part(
    const int* __restrict__ ei, int* __restrict__ tail,
    int* __restrict__ buf, int E)
{
  __shared__ int sPair[EPB];
  __shared__ unsigned char sKey[EPB];
  __shared__ int sHist[256];
  __shared__ int sBase[256];
  const int tid = threadIdx.x;
  sHist[tid] = 0; __syncthreads();
  const int e0 = blockIdx.x * EPB;
  int m = E - e0; if (m > EPB) m = EPB;
  for (int i = tid; i < m; i += 256) {
    int d = ei[E + e0 + i], s = ei[e0 + i];
    sPair[i] = ((d & 255) << 16) | s;
    int b = d >> 8;
    sKey[i] = (unsigned char)b;
    atomicAdd(&sHist[b], 1);
  }
  __syncthreads();
  int c = sHist[tid];
  sBase[tid] = c ? iadd(&tail[tid], c) : 0;
  sHist[tid] = 0;                       // reuse as cursor
  __syncthreads();
  for (int i = tid; i < m; i += 256) {
    int b = sKey[i];
    int off = atomicAdd(&sHist[b], 1);
    buf[sBase[b] + off] = sPair[i];
  }
}

// per-bucket: LDS hist of dst counts (incl. self-loop) + LDS scan -> offs
__global__ __launch_bounds__(256) void k_coffs(
    const int* __restrict__ buf, const int* __restrict__ bufOffs,
    int* __restrict__ offs, int n)
{
  __shared__ int h[256];
  const int b = blockIdx.x, tid = threadIdx.x;
  const int d = (b << 8) + tid;
  h[tid] = (d < n) ? 1 : 0;             // self-loop
  __syncthreads();
  const int lo = bufOffs[b], hi = bufOffs[b + 1];
  for (int i = lo + tid; i < hi; i += 256)
    atomicAdd(&h[(buf[i] >> 16) & 255], 1);
  __syncthreads();
  const int cnt = h[tid];
  for (int off = 1; off < 256; off <<= 1) {
    int t = (tid >= off) ? h[tid - off] : 0;
    __syncthreads();
    h[tid] += t;
    __syncthreads();
  }
  const int excl = h[tid] - cnt;
  const int base = lo + (b << 8);       // edges before bucket + self-loops before
  if (d < n) {
    offs[d] = base + excl;
    if (d == n - 1) offs[n] = base + excl + cnt;
  }
}

// per-bucket scatter into csr with LDS cursors; self-loop first
__global__ __launch_bounds__(256) void k_cscat(
    const int* __restrict__ buf, const int* __restrict__ bufOffs,
    const int* __restrict__ offs, int* __restrict__ csr, int n)
{
  __shared__ int cur[256];
  const int b = blockIdx.x, tid = threadIdx.x;
  const int d = (b << 8) + tid;
  if (d < n) { int o = offs[d]; csr[o] = d; cur[tid] = o + 1; }
  __syncthreads();
  const int lo = bufOffs[b], hi = bufOffs[b + 1];
  for (int i = lo + tid; i < hi; i += 256) {
    int p = buf[i];
    int pos = atomicAdd(&cur[(p >> 16) & 255], 1);
    csr[pos] = p & 0xFFFF;
  }
}

// ---- K1: embedding gather + x@W1 (128->64) + attention dots ---------------
__global__ __launch_bounds__(256) void k_embed_proj1(
    const int* __restrict__ x_ids, const float* __restrict__ emb,
    const float* __restrict__ W1, const float* __restrict__ a_src1,
    const float* __restrict__ a_dst1,
    float* __restrict__ xp1, float* __restrict__ asrc1, float* __restrict__ adst1,
    int n)
{
  __shared__ float sW[128 * 64];
  __shared__ float sx[4][128];
  for (int i = threadIdx.x; i < 128 * 64; i += 256) sW[i] = W1[i];
  const int ln = threadIdx.x >> 6;
  const int ch = threadIdx.x & 63;
  const int hh = ch >> 3, cc = ch & 7;
  const float as = a_src1[ch];
  const float ad = a_dst1[ch];
  for (int g = 0; g < 8; ++g) {
    const int base = blockIdx.x * 32 + g * 4;
    __syncthreads();
    for (int i = threadIdx.x; i < 512; i += 256) {
      int l = i >> 7, k = i & 127;
      int node = base + l;
      sx[l][k] = (node < n) ? emb[(size_t)x_ids[node] * 128 + k] : 0.f;
    }
    __syncthreads();
    const int node = base + ln;
    float acc = 0.f;
#pragma unroll
    for (int k = 0; k < 128; ++k) acc = fmaf(sx[ln][k], sW[k * 64 + ch], acc);
    float vs = acc * as, vd = acc * ad;
    vs += __shfl_xor(vs, 1); vs += __shfl_xor(vs, 2); vs += __shfl_xor(vs, 4);
    vd += __shfl_xor(vd, 1); vd += __shfl_xor(vd, 2); vd += __shfl_xor(vd, 4);
    if (node < n) {
      xp1[(size_t)node * 64 + ch] = acc;
      if (cc == 0) { asrc1[node * 8 + hh] = vs; adst1[node * 8 + hh] = vd; }
    }
  }
}

// ---- G1: layer-1 gather-aggregate + ELU + fused 64->20 projection ---------
__global__ __launch_bounds__(256) void k_gather1(
    const int* __restrict__ offs, const int* __restrict__ csr,
    const float* __restrict__ asrc1, const float* __restrict__ adst1,
    const float* __restrict__ xp1, const float* __restrict__ b1,
    const float* __restrict__ W2, const float* __restrict__ a_src2,
    const float* __restrict__ a_dst2,
    float* __restrict__ xp2, float* __restrict__ asrc2, float* __restrict__ adst2,
    int n)
{
  __shared__ float sW[64 * 20];
  __shared__ float sh[4][64];
  for (int i = threadIdx.x; i < 64 * 20; i += 256) sW[i] = W2[i];
  __syncthreads();
  const int wid = threadIdx.x >> 6;
  const int ln  = threadIdx.x & 63;
  const int eslot = ln >> 4;
  const int q     = ln & 15;
  const int hh    = q >> 1;
  const int d = blockIdx.x * 4 + wid;
  const bool valid = d < n;
  const int beg = valid ? offs[d] : 0;
  const int end = valid ? offs[d + 1] : 0;
  const float adT = valid ? adst1[(size_t)d * 8 + hh] : 0.f;
  float a0 = 0.f, a1 = 0.f, a2 = 0.f, a3 = 0.f, den = 0.f;
#pragma unroll 4
  for (int jb = beg + eslot; jb < end; jb += 4) {
    const int s = csr[jb];
    const float p = __expf(lrelu(asrc1[(size_t)s * 8 + hh] + adT));
    const float4 v = *(const float4*)(xp1 + (size_t)s * 64 + q * 4);
    a0 = fmaf(p, v.x, a0); a1 = fmaf(p, v.y, a1);
    a2 = fmaf(p, v.z, a2); a3 = fmaf(p, v.w, a3);
    den += p;
  }
#pragma unroll
  for (int off = 16; off < 64; off <<= 1) {
    a0 += __shfl_xor(a0, off); a1 += __shfl_xor(a1, off);
    a2 += __shfl_xor(a2, off); a3 += __shfl_xor(a3, off);
    den += __shfl_xor(den, off);
  }
  if (valid && eslot == 0) {
    const float inv = 1.f / den;
    float t0 = a0 * inv + b1[q * 4 + 0];
    float t1 = a1 * inv + b1[q * 4 + 1];
    float t2 = a2 * inv + b1[q * 4 + 2];
    float t3 = a3 * inv + b1[q * 4 + 3];
    sh[wid][q * 4 + 0] = t0 > 0.f ? t0 : expm1f(t0);
    sh[wid][q * 4 + 1] = t1 > 0.f ? t1 : expm1f(t1);
    sh[wid][q * 4 + 2] = t2 > 0.f ? t2 : expm1f(t2);
    sh[wid][q * 4 + 3] = t3 > 0.f ? t3 : expm1f(t3);
  }
  __syncthreads();
  float acc2 = 0.f;
  if (valid && ln < 20) {
#pragma unroll 16
    for (int k = 0; k < 64; ++k) acc2 = fmaf(sh[wid][k], sW[k * 20 + ln], acc2);
    xp2[(size_t)d * 20 + ln] = acc2;
  }
  float vs = (valid && ln < 20) ? acc2 * a_src2[ln] : 0.f;
  float vd = (valid && ln < 20) ? acc2 * a_dst2[ln] : 0.f;
#pragma unroll
  for (int off = 1; off < 32; off <<= 1) {
    vs += __shfl_xor(vs, off);
    vd += __shfl_xor(vd, off);
  }
  if (valid && ln == 0) { asrc2[d] = vs; adst2[d] = vd; }
}

// ---- G2: layer-2 gather-aggregate + fused log_softmax -> out --------------
__global__ __launch_bounds__(256) void k_gather2(
    const int* __restrict__ offs, const int* __restrict__ csr,
    const float* __restrict__ asrc2, const float* __restrict__ adst2,
    const float* __restrict__ xp2, const float* __restrict__ b2,
    float* __restrict__ out, int n)
{
  const int wid = threadIdx.x >> 6, ln = threadIdx.x & 63;
  const int eslot = ln >> 2, q = ln & 3;
  const int d = blockIdx.x * 4 + wid;
  if (d >= n) return;
  const int beg = offs[d], end = offs[d + 1];
  const float adT = adst2[d];
  float acc[5] = {0.f, 0.f, 0.f, 0.f, 0.f};
  float den = 0.f;
#pragma unroll 2
  for (int jb = beg + eslot; jb < end; jb += 16) {
    const int s = csr[jb];
    const float p = __expf(lrelu(asrc2[s] + adT));
    const float* row = xp2 + (size_t)s * 20 + q * 5;
#pragma unroll
    for (int j = 0; j < 5; ++j) acc[j] = fmaf(p, row[j], acc[j]);
    den += p;
  }
#pragma unroll
  for (int off = 4; off < 64; off <<= 1) {
#pragma unroll
    for (int j = 0; j < 5; ++j) acc[j] += __shfl_xor(acc[j], off);
    den += __shfl_xor(den, off);
  }
  const float inv = 1.f / den;
  float o[5], mx = -1e30f;
#pragma unroll
  for (int j = 0; j < 5; ++j) {
    o[j] = acc[j] * inv + b2[q * 5 + j];
    mx = fmaxf(mx, o[j]);
  }
  mx = fmaxf(mx, __shfl_xor(mx, 1));
  mx = fmaxf(mx, __shfl_xor(mx, 2));
  float ss = 0.f;
#pragma unroll
  for (int j = 0; j < 5; ++j) ss += __expf(o[j] - mx);
  ss += __shfl_xor(ss, 1);
  ss += __shfl_xor(ss, 2);
  const float lse = mx + __logf(ss);
  if (eslot == 0) {
#pragma unroll
    for (int j = 0; j < 5; ++j) out[(size_t)d * 20 + q * 5 + j] = o[j] - lse;
  }
}

// ---------------------------------------------------------------------------

extern "C" void kernel_launch(void* const* d_in, const int* in_sizes, int n_in,
                              void* d_out, int out_size, void* d_ws, size_t ws_size,
                              hipStream_t stream)
{
  const int*   x_ids  = (const int*)d_in[0];
  const int*   ei     = (const int*)d_in[1];   // [2,E]: [0..E)=src, [E..2E)=dst
  const float* emb    = (const float*)d_in[2];
  const float* W1     = (const float*)d_in[3];
  const float* a_src1 = (const float*)d_in[4];
  const float* a_dst1 = (const float*)d_in[5];
  const float* b1     = (const float*)d_in[6];
  const float* W2     = (const float*)d_in[7];
  const float* a_src2 = (const float*)d_in[8];
  const float* a_dst2 = (const float*)d_in[9];
  const float* b2     = (const float*)d_in[10];
  float* out = (float*)d_out;

  const int n = in_sizes[0];
  const int E = in_sizes[1] / 2;
  const int nb = (n + 255) >> 8;               // buckets of 256 dst ids

  float* ws    = (float*)d_ws;
  float* xp1   = ws;                          // n*64  (aliases buf during build)
  float* asrc1 = xp1   + (size_t)n * 64;      // n*8
  float* adst1 = asrc1 + (size_t)n * 8;       // n*8
  float* xp2   = adst1 + (size_t)n * 8;       // n*20
  float* asrc2 = xp2   + (size_t)n * 20;      // n
  float* adst2 = asrc2 + (size_t)n;           // n
  int*   offs   = (int*)(adst2 + (size_t)n);  // n+1
  int*   bhist  = offs + n + 1;               // 256 (zeroed)
  int*   bufOffs= bhist + 256;                // nb+1
  int*   tail   = bufOffs + 257;              // 256
  int*   csr    = tail + 256;                 // E+n
  int*   buf    = (int*)xp1;                  // E   (dead before k_embed_proj1)

  hipMemsetAsync(bhist, 0, 256 * sizeof(int), stream);

  k_bhist<<<256, 256, 0, stream>>>(ei, bhist, E);
  k_bscan<<<1, 256, 0, stream>>>(bhist, bufOffs, tail, nb);
  k_part<<<(E + EPB - 1) / EPB, 256, 0, stream>>>(ei, tail, buf, E);
  k_coffs<<<nb, 256, 0, stream>>>(buf, bufOffs, offs, n);
  k_cscat<<<nb, 256, 0, stream>>>(buf, bufOffs, offs, csr, n);

  k_embed_proj1<<<(n + 31) / 32, 256, 0, stream>>>(
      x_ids, emb, W1, a_src1, a_dst1, xp1, asrc1, adst1, n);

  k_gather1<<<(n + 3) / 4, 256, 0, stream>>>(
      offs, csr, asrc1, adst1, xp1, b1, W2, a_src2, a_dst2,
      xp2, asrc2, adst2, n);

  k_gather2<<<(n + 3) / 4, 256, 0, stream>>>(
      offs, csr, asrc2, adst2, xp2, b2, out, n);
}

// Round 7
// 218.280 us; speedup vs baseline: 1.8140x; 1.0991x over previous
//
#include <hip/hip_runtime.h>
#include <cstddef>

// ---------------------------------------------------------------------------
// 2-layer GAT forward, CSR-gather formulation.
// R7: xp1 stored as bf16 (halves the 203MB random-gather traffic in k_gather1);
// k_embed_proj1 uses transposed padded W1 in LDS (float4 reads, 2 nodes/wave).
// Requires n < 65536 (src id packed in 16 bits); here n = 50000.
// ---------------------------------------------------------------------------

#define EPB 2048   // edges per k_part block

__device__ __forceinline__ float lrelu(float x) { return x > 0.f ? x : 0.2f * x; }
__device__ __forceinline__ int iadd(int* p, int v) {
  return __hip_atomic_fetch_add(p, v, __ATOMIC_RELAXED, __HIP_MEMORY_SCOPE_AGENT);
}
__device__ __forceinline__ unsigned short f2bf(float f) {   // RNE float->bf16
  unsigned int u = __float_as_uint(f);
  u += 0x7FFFu + ((u >> 16) & 1u);
  return (unsigned short)(u >> 16);
}

// ---- CSR build ------------------------------------------------------------

__global__ __launch_bounds__(256) void k_bhist(
    const int* __restrict__ ei, int* __restrict__ bhist, int E)
{
  __shared__ int h[256];
  h[threadIdx.x] = 0; __syncthreads();
  for (int e = blockIdx.x * 256 + threadIdx.x; e < E; e += gridDim.x * 256)
    atomicAdd(&h[ei[E + e] >> 8], 1);
  __syncthreads();
  int c = h[threadIdx.x];
  if (c) iadd(&bhist[threadIdx.x], c);
}

__global__ __launch_bounds__(256) void k_bscan(
    const int* __restrict__ bhist, int* __restrict__ bufOffs,
    int* __restrict__ tail, int nb)
{
  __shared__ int sp[256];
  const int tid = threadIdx.x;
  int v = (tid < nb) ? bhist[tid] : 0;
  sp[tid] = v; __syncthreads();
  for (int off = 1; off < 256; off <<= 1) {
    int t = (tid >= off) ? sp[tid - off] : 0;
    __syncthreads();
    sp[tid] += t;
    __syncthreads();
  }
  int excl = sp[tid] - v;
  if (tid < nb) { bufOffs[tid] = excl; tail[tid] = excl; }
  if (tid == 255) bufOffs[nb] = sp[255];
}

__global__ __launch_bounds__(256) void k_part(
    const int* __restrict__ ei, int* __restrict__ tail,
    int* __restrict__ buf, int E)
{
  __shared__ int sPair[EPB];
  __shared__ unsigned char sKey[EPB];
  __shared__ int sHist[256];
  __shared__ int sBase[256];
  const int tid = threadIdx.x;
  sHist[tid] = 0; __syncthreads();
  const int e0 = blockIdx.x * EPB;
  int m = E - e0; if (m > EPB) m = EPB;
  for (int i = tid; i < m; i += 256) {
    int d = ei[E + e0 + i], s = ei[e0 + i];
    sPair[i] = ((d & 255) << 16) | s;
    int b = d >> 8;
    sKey[i] = (unsigned char)b;
    atomicAdd(&sHist[b], 1);
  }
  __syncthreads();
  int c = sHist[tid];
  sBase[tid] = c ? iadd(&tail[tid], c) : 0;
  sHist[tid] = 0;
  __syncthreads();
  for (int i = tid; i < m; i += 256) {
    int b = sKey[i];
    int off = atomicAdd(&sHist[b], 1);
    buf[sBase[b] + off] = sPair[i];
  }
}

// per-bucket: LDS hist (incl. self-loop) + LDS scan -> offs directly
__global__ __launch_bounds__(256) void k_coffs(
    const int* __restrict__ buf, const int* __restrict__ bufOffs,
    int* __restrict__ offs, int n)
{
  __shared__ int h[256];
  const int b = blockIdx.x, tid = threadIdx.x;
  const int d = (b << 8) + tid;
  h[tid] = (d < n) ? 1 : 0;
  __syncthreads();
  const int lo = bufOffs[b], hi = bufOffs[b + 1];
  for (int i = lo + tid; i < hi; i += 256)
    atomicAdd(&h[(buf[i] >> 16) & 255], 1);
  __syncthreads();
  const int cnt = h[tid];
  for (int off = 1; off < 256; off <<= 1) {
    int t = (tid >= off) ? h[tid - off] : 0;
    __syncthreads();
    h[tid] += t;
    __syncthreads();
  }
  const int excl = h[tid] - cnt;
  const int base = lo + (b << 8);
  if (d < n) {
    offs[d] = base + excl;
    if (d == n - 1) offs[n] = base + excl + cnt;
  }
}

__global__ __launch_bounds__(256) void k_cscat(
    const int* __restrict__ buf, const int* __restrict__ bufOffs,
    const int* __restrict__ offs, int* __restrict__ csr, int n)
{
  __shared__ int cur[256];
  const int b = blockIdx.x, tid = threadIdx.x;
  const int d = (b << 8) + tid;
  if (d < n) { int o = offs[d]; csr[o] = d; cur[tid] = o + 1; }
  __syncthreads();
  const int lo = bufOffs[b], hi = bufOffs[b + 1];
  for (int i = lo + tid; i < hi; i += 256) {
    int p = buf[i];
    int pos = atomicAdd(&cur[(p >> 16) & 255], 1);
    csr[pos] = p & 0xFFFF;
  }
}

// ---- K1: embedding gather + x@W1 (128->64, via transposed LDS W) ----------
// 2 nodes per wave, 8 nodes per group-iteration, 32 nodes per block.
__global__ __launch_bounds__(256) void k_embed_proj1(
    const int* __restrict__ x_ids, const float* __restrict__ emb,
    const float* __restrict__ W1, const float* __restrict__ a_src1,
    const float* __restrict__ a_dst1,
    unsigned short* __restrict__ xp1b, float* __restrict__ asrc1,
    float* __restrict__ adst1, int n)
{
  __shared__ float sWT[64 * 132];          // transposed W1, pad 132 (33.8 KB)
  __shared__ float sx[8][128];
  for (int i = threadIdx.x; i < 128 * 64; i += 256) {
    int k = i >> 6, c = i & 63;
    sWT[c * 132 + k] = W1[i];
  }
  const int wid = threadIdx.x >> 6;        // wave 0..3
  const int ch  = threadIdx.x & 63;        // channel h*8+c
  const int hh = ch >> 3, cc = ch & 7;
  const float as = a_src1[ch];
  const float ad = a_dst1[ch];
  const float* wrow = sWT + ch * 132;
  for (int g = 0; g < 4; ++g) {
    const int base = blockIdx.x * 32 + g * 8;
    __syncthreads();                       // protects sWT (g==0) and sx reuse
    for (int i = threadIdx.x; i < 1024; i += 256) {
      int l = i >> 7, k = i & 127;
      int node = base + l;
      sx[l][k] = (node < n) ? emb[(size_t)x_ids[node] * 128 + k] : 0.f;
    }
    __syncthreads();
    const int l0 = wid * 2, l1 = l0 + 1;
    float acc0 = 0.f, acc1 = 0.f;
#pragma unroll 8
    for (int k = 0; k < 128; k += 4) {
      const float4 wv = *(const float4*)(wrow + k);
      const float4 x0 = *(const float4*)(&sx[l0][k]);
      const float4 x1 = *(const float4*)(&sx[l1][k]);
      acc0 = fmaf(x0.x, wv.x, acc0); acc1 = fmaf(x1.x, wv.x, acc1);
      acc0 = fmaf(x0.y, wv.y, acc0); acc1 = fmaf(x1.y, wv.y, acc1);
      acc0 = fmaf(x0.z, wv.z, acc0); acc1 = fmaf(x1.z, wv.z, acc1);
      acc0 = fmaf(x0.w, wv.w, acc0); acc1 = fmaf(x1.w, wv.w, acc1);
    }
    float vs0 = acc0 * as, vd0 = acc0 * ad;
    float vs1 = acc1 * as, vd1 = acc1 * ad;
    vs0 += __shfl_xor(vs0, 1); vs0 += __shfl_xor(vs0, 2); vs0 += __shfl_xor(vs0, 4);
    vd0 += __shfl_xor(vd0, 1); vd0 += __shfl_xor(vd0, 2); vd0 += __shfl_xor(vd0, 4);
    vs1 += __shfl_xor(vs1, 1); vs1 += __shfl_xor(vs1, 2); vs1 += __shfl_xor(vs1, 4);
    vd1 += __shfl_xor(vd1, 1); vd1 += __shfl_xor(vd1, 2); vd1 += __shfl_xor(vd1, 4);
    const int node0 = base + l0, node1 = base + l1;
    if (node0 < n) {
      xp1b[(size_t)node0 * 64 + ch] = f2bf(acc0);
      if (cc == 0) { asrc1[node0 * 8 + hh] = vs0; adst1[node0 * 8 + hh] = vd0; }
    }
    if (node1 < n) {
      xp1b[(size_t)node1 * 64 + ch] = f2bf(acc1);
      if (cc == 0) { asrc1[node1 * 8 + hh] = vs1; adst1[node1 * 8 + hh] = vd1; }
    }
  }
}

// ---- G1: layer-1 gather-aggregate (bf16 rows) + ELU + fused 64->20 proj ---
__global__ __launch_bounds__(256) void k_gather1(
    const int* __restrict__ offs, const int* __restrict__ csr,
    const float* __restrict__ asrc1, const float* __restrict__ adst1,
    const unsigned short* __restrict__ xp1b, const float* __restrict__ b1,
    const float* __restrict__ W2, const float* __restrict__ a_src2,
    const float* __restrict__ a_dst2,
    float* __restrict__ xp2, float* __restrict__ asrc2, float* __restrict__ adst2,
    int n)
{
  __shared__ float sW[64 * 20];
  __shared__ float sh[4][64];
  for (int i = threadIdx.x; i < 64 * 20; i += 256) sW[i] = W2[i];
  __syncthreads();
  const int wid = threadIdx.x >> 6;
  const int ln  = threadIdx.x & 63;
  const int eslot = ln >> 4;          // edge slot 0..3
  const int q     = ln & 15;          // channel quad
  const int hh    = q >> 1;           // head
  const int d = blockIdx.x * 4 + wid;
  const bool valid = d < n;
  const int beg = valid ? offs[d] : 0;
  const int end = valid ? offs[d + 1] : 0;
  const float adT = valid ? adst1[(size_t)d * 8 + hh] : 0.f;
  float a0 = 0.f, a1 = 0.f, a2 = 0.f, a3 = 0.f, den = 0.f;
#pragma unroll 4
  for (int jb = beg + eslot; jb < end; jb += 4) {
    const int s = csr[jb];
    const float p = __expf(lrelu(asrc1[(size_t)s * 8 + hh] + adT));
    const uint2 u = *(const uint2*)(xp1b + (size_t)s * 64 + (q << 2));
    a0 = fmaf(p, __uint_as_float(u.x << 16), a0);
    a1 = fmaf(p, __uint_as_float(u.x & 0xFFFF0000u), a1);
    a2 = fmaf(p, __uint_as_float(u.y << 16), a2);
    a3 = fmaf(p, __uint_as_float(u.y & 0xFFFF0000u), a3);
    den += p;
  }
#pragma unroll
  for (int off = 16; off < 64; off <<= 1) {
    a0 += __shfl_xor(a0, off); a1 += __shfl_xor(a1, off);
    a2 += __shfl_xor(a2, off); a3 += __shfl_xor(a3, off);
    den += __shfl_xor(den, off);
  }
  if (valid && eslot == 0) {
    const float inv = 1.f / den;
    float t0 = a0 * inv + b1[q * 4 + 0];
    float t1 = a1 * inv + b1[q * 4 + 1];
    float t2 = a2 * inv + b1[q * 4 + 2];
    float t3 = a3 * inv + b1[q * 4 + 3];
    sh[wid][q * 4 + 0] = t0 > 0.f ? t0 : expm1f(t0);
    sh[wid][q * 4 + 1] = t1 > 0.f ? t1 : expm1f(t1);
    sh[wid][q * 4 + 2] = t2 > 0.f ? t2 : expm1f(t2);
    sh[wid][q * 4 + 3] = t3 > 0.f ? t3 : expm1f(t3);
  }
  __syncthreads();
  float acc2 = 0.f;
  if (valid && ln < 20) {
#pragma unroll 16
    for (int k = 0; k < 64; ++k) acc2 = fmaf(sh[wid][k], sW[k * 20 + ln], acc2);
    xp2[(size_t)d * 20 + ln] = acc2;
  }
  float vs = (valid && ln < 20) ? acc2 * a_src2[ln] : 0.f;
  float vd = (valid && ln < 20) ? acc2 * a_dst2[ln] : 0.f;
#pragma unroll
  for (int off = 1; off < 32; off <<= 1) {
    vs += __shfl_xor(vs, off);
    vd += __shfl_xor(vd, off);
  }
  if (valid && ln == 0) { asrc2[d] = vs; adst2[d] = vd; }
}

// ---- G2: layer-2 gather-aggregate + fused log_softmax -> out --------------
__global__ __launch_bounds__(256) void k_gather2(
    const int* __restrict__ offs, const int* __restrict__ csr,
    const float* __restrict__ asrc2, const float* __restrict__ adst2,
    const float* __restrict__ xp2, const float* __restrict__ b2,
    float* __restrict__ out, int n)
{
  const int wid = threadIdx.x >> 6, ln = threadIdx.x & 63;
  const int eslot = ln >> 2, q = ln & 3;
  const int d = blockIdx.x * 4 + wid;
  if (d >= n) return;
  const int beg = offs[d], end = offs[d + 1];
  const float adT = adst2[d];
  float acc[5] = {0.f, 0.f, 0.f, 0.f, 0.f};
  float den = 0.f;
#pragma unroll 2
  for (int jb = beg + eslot; jb < end; jb += 16) {
    const int s = csr[jb];
    const float p = __expf(lrelu(asrc2[s] + adT));
    const float* row = xp2 + (size_t)s * 20 + q * 5;
#pragma unroll
    for (int j = 0; j < 5; ++j) acc[j] = fmaf(p, row[j], acc[j]);
    den += p;
  }
#pragma unroll
  for (int off = 4; off < 64; off <<= 1) {
#pragma unroll
    for (int j = 0; j < 5; ++j) acc[j] += __shfl_xor(acc[j], off);
    den += __shfl_xor(den, off);
  }
  const float inv = 1.f / den;
  float o[5], mx = -1e30f;
#pragma unroll
  for (int j = 0; j < 5; ++j) {
    o[j] = acc[j] * inv + b2[q * 5 + j];
    mx = fmaxf(mx, o[j]);
  }
  mx = fmaxf(mx, __shfl_xor(mx, 1));
  mx = fmaxf(mx, __shfl_xor(mx, 2));
  float ss = 0.f;
#pragma unroll
  for (int j = 0; j < 5; ++j) ss += __expf(o[j] - mx);
  ss += __shfl_xor(ss, 1);
  ss += __shfl_xor(ss, 2);
  const float lse = mx + __logf(ss);
  if (eslot == 0) {
#pragma unroll
    for (int j = 0; j < 5; ++j) out[(size_t)d * 20 + q * 5 + j] = o[j] - lse;
  }
}

// ---------------------------------------------------------------------------

extern "C" void kernel_launch(void* const* d_in, const int* in_sizes, int n_in,
                              void* d_out, int out_size, void* d_ws, size_t ws_size,
                              hipStream_t stream)
{
  const int*   x_ids  = (const int*)d_in[0];
  const int*   ei     = (const int*)d_in[1];   // [2,E]: [0..E)=src, [E..2E)=dst
  const float* emb    = (const float*)d_in[2];
  const float* W1     = (const float*)d_in[3];
  const float* a_src1 = (const float*)d_in[4];
  const float* a_dst1 = (const float*)d_in[5];
  const float* b1     = (const float*)d_in[6];
  const float* W2     = (const float*)d_in[7];
  const float* a_src2 = (const float*)d_in[8];
  const float* a_dst2 = (const float*)d_in[9];
  const float* b2     = (const float*)d_in[10];
  float* out = (float*)d_out;

  const int n = in_sizes[0];
  const int E = in_sizes[1] / 2;
  const int nb = (n + 255) >> 8;               // buckets of 256 dst ids

  // workspace layout (bytes). xp1b (bf16) aliases buf (build-phase only).
  char* base = (char*)d_ws;
  size_t r0 = (size_t)n * 128;                 // xp1b: n*64*2 B
  if ((size_t)E * 4 > r0) r0 = (size_t)E * 4;  // buf:  E*4 B
  r0 = (r0 + 255) & ~(size_t)255;
  unsigned short* xp1b = (unsigned short*)base;
  int*   buf   = (int*)base;
  float* asrc1 = (float*)(base + r0);          // n*8
  float* adst1 = asrc1 + (size_t)n * 8;        // n*8
  float* xp2   = adst1 + (size_t)n * 8;        // n*20
  float* asrc2 = xp2   + (size_t)n * 20;       // n
  float* adst2 = asrc2 + (size_t)n;            // n
  int*   offs   = (int*)(adst2 + (size_t)n);   // n+1
  int*   bhist  = offs + n + 1;                // 256 (zeroed)
  int*   bufOffs= bhist + 256;                 // nb+1
  int*   tail   = bufOffs + 257;               // 256
  int*   csr    = tail + 256;                  // E+n

  hipMemsetAsync(bhist, 0, 256 * sizeof(int), stream);

  k_bhist<<<256, 256, 0, stream>>>(ei, bhist, E);
  k_bscan<<<1, 256, 0, stream>>>(bhist, bufOffs, tail, nb);
  k_part<<<(E + EPB - 1) / EPB, 256, 0, stream>>>(ei, tail, buf, E);
  k_coffs<<<nb, 256, 0, stream>>>(buf, bufOffs, offs, n);
  k_cscat<<<nb, 256, 0, stream>>>(buf, bufOffs, offs, csr, n);

  k_embed_proj1<<<(n + 31) / 32, 256, 0, stream>>>(
      x_ids, emb, W1, a_src1, a_dst1, xp1b, asrc1, adst1, n);

  k_gather1<<<(n + 3) / 4, 256, 0, stream>>>(
      offs, csr, asrc1, adst1, xp1b, b1, W2, a_src2, a_dst2,
      xp2, asrc2, adst2, n);

  k_gather2<<<(n + 3) / 4, 256, 0, stream>>>(
      offs, csr, asrc2, adst2, xp2, b2, out, n);
}